// Round 7
// baseline (1201.569 us; speedup 1.0000x reference)
//
#include <hip/hip_runtime.h>
#include <math.h>

#define T_STEPS 512
#define NF 4
#define HID 32
#define BN_EPS 1e-5f

typedef float    f32x2 __attribute__((ext_vector_type(2)));
typedef float    f32x4 __attribute__((ext_vector_type(4)));
typedef _Float16 f16x2 __attribute__((ext_vector_type(2)));
typedef _Float16 f16x8 __attribute__((ext_vector_type(8)));

struct H8 { f16x2 p[4]; };   // bit_cast view of f16x8: p[q] == one VGPR, zero-cost

__device__ __forceinline__ f16x2 pk16(float x, float y) {
  return __builtin_bit_cast(f16x2, __builtin_amdgcn_cvt_pkrtz(x, y));
}
__device__ __forceinline__ float fdot2(f16x2 a, f16x2 b, float c) {
  return __builtin_amdgcn_fdot2(a, b, c, false);   // v_dot2_f32_f16: 2 MACs, fp32 acc
}
__device__ __forceinline__ float fsigmoid(float x) {
  return __builtin_amdgcn_rcpf(1.0f + __expf(-x));   // validated r1..r6: absmax 2e-3
}
__device__ __forceinline__ float ftanh(float x) {
  return fmaf(__builtin_amdgcn_rcpf(1.0f + __expf(-2.0f * x)), 2.0f, -1.0f);
}
template <int CTRL>
__device__ __forceinline__ float dpp_add(float v) {
  int s = __builtin_amdgcn_update_dpp(0, __builtin_bit_cast(int, v), CTRL, 0xf, 0xf, true);
  return v + __builtin_bit_cast(float, s);
}

// ONE batch row per wave (r6 had 2): per-wave issue halves, wave count doubles
// (8192 waves = 8/SIMD at VGPR<=64), activations split across wave-halves.
// Lane: u = lane&31, half = lane>>5. Lower owns gate-rows i_u,f_u + the c-chain;
// upper owns g_u,o_u + produces h. Unified activation a*sig(k*x)+b keeps both
// halves on one instruction stream (8 transcendentals/step vs 12 in r6).
__global__ __launch_bounds__(256, 8) void hedge_kernel(
    const float* __restrict__ x,
    const float* __restrict__ bn_g, const float* __restrict__ bn_b,
    const float* __restrict__ bn_m, const float* __restrict__ bn_v,
    const float* __restrict__ W_ih, const float* __restrict__ b_ih,
    const float* __restrict__ W_hh, const float* __restrict__ b_hh,
    const float* __restrict__ W1,   const float* __restrict__ b1,
    const float* __restrict__ W2,   const float* __restrict__ b2,
    float* __restrict__ out)
{
  __shared__ __align__(16) _Float16 sh[4][HID];   // [wave][unit], 256 B

  const int tid  = threadIdx.x;
  const int u    = tid & 31;
  const int half = tid >> 5 & 1;
  const int wv   = __builtin_amdgcn_readfirstlane(tid >> 6);
  const int row  = blockIdx.x * 4 + wv;

  // ---- fold BatchNorm (z*scale + shift) into W_ih' and bias
  float scale[5], shift[5];
  #pragma unroll
  for (int f = 0; f < 5; ++f) {
    float s = bn_g[f] * rsqrtf(bn_v[f] + BN_EPS);
    scale[f] = s;
    shift[f] = fmaf(-bn_m[f], s, bn_b[f]);
  }

  // gate rows owned by this lane (torch order i,f,g,o):
  //   lower: r0 = u (i), r1 = 32+u (f);  upper: r0 = 64+u (g), r1 = 96+u (o)
  const int r0 = half * 64 + u;
  const int r1 = r0 + 32;

  f16x2 wh0[16], wh1[16];           // W_hh rows r0,r1 as f16 pairs (32 VGPRs)
  f16x2 wx0a, wx0b, wx1a, wx1b;     // BN-scaled x-weights (4 VGPRs)
  float wd0, wd1, bias0, bias1;
  {
    float ws[5], acc = b_ih[r0] + b_hh[r0];
    #pragma unroll
    for (int f = 0; f < 5; ++f) {
      float w = W_ih[r0 * 5 + f];
      ws[f] = w * scale[f];
      acc = fmaf(w, shift[f], acc);
    }
    wx0a = pk16(ws[0], ws[1]);
    wx0b = pk16(ws[2], ws[3]);
    wd0 = ws[4]; bias0 = acc;
    #pragma unroll
    for (int p = 0; p < 16; ++p) {
      f32x2 w = *(const f32x2*)&W_hh[r0 * HID + 2 * p];
      wh0[p] = pk16(w.x, w.y);
    }
  }
  {
    float ws[5], acc = b_ih[r1] + b_hh[r1];
    #pragma unroll
    for (int f = 0; f < 5; ++f) {
      float w = W_ih[r1 * 5 + f];
      ws[f] = w * scale[f];
      acc = fmaf(w, shift[f], acc);
    }
    wx1a = pk16(ws[0], ws[1]);
    wx1b = pk16(ws[2], ws[3]);
    wd1 = ws[4]; bias1 = acc;
    #pragma unroll
    for (int p = 0; p < 16; ++p) {
      f32x2 w = *(const f32x2*)&W_hh[r1 * HID + 2 * p];
      wh1[p] = pk16(w.x, w.y);
    }
  }

  // MLP: lane = unit u, k-half [half*16, half*16+16) (4 VGPRs)
  f16x2 w1h[8];
  #pragma unroll
  for (int p = 0; p < 8; ++p) {
    f32x2 w = *(const f32x2*)&W1[u * HID + half * 16 + 2 * p];
    w1h[p] = pk16(w.x, w.y);
  }
  const float b1u = b1[u];
  const float w2u = W2[u];
  const float b2s = b2[0];

  // unified activation constants: A0 = k0a*sig(-nk0... )  lower: sigmoid, upper: tanh
  const float nk0 = half ? -2.0f : -1.0f;
  const float k0a = half ?  2.0f :  1.0f;
  const float b0c = half ? -1.0f :  0.0f;

  const float* xrow = x + (size_t)row * (T_STEPS * NF);
  float*       orow = out + (size_t)row * T_STEPS;

  float c = 0.0f;

  // gate accumulators for r0/r1; init = bias + x_0 (h_{-1}=d_{-1}=0)
  float acc0, acc1;
  {
    const f32x4 x0 = *(const f32x4*)xrow;      // all 64 lanes same addr: broadcast
    const f16x2 x01 = pk16(x0.x, x0.y), x23 = pk16(x0.z, x0.w);
    acc0 = fdot2(wx0b, x23, fdot2(wx0a, x01, bias0));
    acc1 = fdot2(wx1b, x23, fdot2(wx1a, x01, bias1));
  }

  #pragma unroll 1
  for (int t = 0; t < T_STEPS; ++t) {
    const int tn = (t + 1 < T_STEPS) ? t + 1 : t;
    const f32x4 xn = *(const f32x4*)(xrow + tn * NF);   // x_{t+1}, dead after re-init

    // ---- activations: A0 = I (lower) / G (upper); A1 = F (lower) / O (upper)
    const float A0 = fmaf(k0a, __builtin_amdgcn_rcpf(1.0f + __expf(nk0 * acc0)), b0c);
    const float A1 = fsigmoid(acc1);
    const float Gx = __shfl_xor(A0, 32);   // lower receives G (upper receives I, unused)
    c = fmaf(A1, c, A0 * Gx);              // lower: F*c + I*G (upper: garbage, never read)
    const float tc  = ftanh(c);            // lower: tanh(c_t)
    const float tcx = __shfl_xor(tc, 32);  // upper receives tanh(c_t)
    const float h   = A1 * tcx;            // upper: O * tanh(c_t)
    if (half) sh[wv][u] = (_Float16)h;     // same-wave producer/consumer: lgkmcnt orders

    // ---- acc(t+1) = bias + x_{t+1} terms
    {
      const f16x2 x01 = pk16(xn.x, xn.y), x23 = pk16(xn.z, xn.w);
      acc0 = fdot2(wx0b, x23, fdot2(wx0a, x01, bias0));
      acc1 = fdot2(wx1b, x23, fdot2(wx1a, x01, bias1));
    }

    // ---- h_t -> gates(t+1): 32 dot2, broadcast b128 LDS reads, zero-cost chunking
    #pragma unroll
    for (int i = 0; i < 4; ++i) {
      const H8 hh = __builtin_bit_cast(H8, *(const f16x8*)&sh[wv][8 * i]);
      #pragma unroll
      for (int q = 0; q < 4; ++q) {
        acc0 = fdot2(wh0[4*i+q], hh.p[q], acc0);
        acc1 = fdot2(wh1[4*i+q], hh.p[q], acc1);
      }
    }

    // ---- decision MLP: unit u, my k-half (8 dot2)
    float pp = 0.0f;
    #pragma unroll
    for (int i = 0; i < 2; ++i) {
      const H8 hm = __builtin_bit_cast(H8, *(const f16x8*)&sh[wv][half * 16 + 8 * i]);
      #pragma unroll
      for (int q = 0; q < 4; ++q) pp = fdot2(w1h[4*i+q], hm.p[q], pp);
    }
    const float m = pp + __shfl_xor(pp, 32) + b1u;   // both halves: full m_u
    float rv = fmaxf(m, 0.0f) * w2u;
    rv = dpp_add<0x111>(rv);   // row_shr:1
    rv = dpp_add<0x112>(rv);   // row_shr:2
    rv = dpp_add<0x114>(rv);   // row_shr:4
    rv = dpp_add<0x118>(rv);   // row_shr:8  -> lane15/31/47/63 hold 16-sums
    rv = dpp_add<0x142>(rv);   // row_bcast:15 -> lane31 = sum(0..31)
    const float sv = fsigmoid(rv + b2s);
    const float d  = __builtin_bit_cast(float,
        __builtin_amdgcn_readlane(__builtin_bit_cast(int, sv), 31));  // uniform

    // d_t term of gates(t+1)
    acc0 = fmaf(wd0, d, acc0);
    acc1 = fmaf(wd1, d, acc1);

    if ((tid & 63) == 0) orow[t] = d;
  }
}

extern "C" void kernel_launch(void* const* d_in, const int* in_sizes, int n_in,
                              void* d_out, int out_size, void* d_ws, size_t ws_size,
                              hipStream_t stream) {
  const float* x    = (const float*)d_in[0];
  const float* bn_g = (const float*)d_in[1];
  const float* bn_b = (const float*)d_in[2];
  const float* bn_m = (const float*)d_in[3];
  const float* bn_v = (const float*)d_in[4];
  const float* W_ih = (const float*)d_in[5];
  const float* b_ih = (const float*)d_in[6];
  const float* W_hh = (const float*)d_in[7];
  const float* b_hh = (const float*)d_in[8];
  const float* W1   = (const float*)d_in[9];
  const float* b1   = (const float*)d_in[10];
  const float* W2   = (const float*)d_in[11];
  const float* b2   = (const float*)d_in[12];
  float* out = (float*)d_out;

  const int B = in_sizes[0] / (T_STEPS * NF);   // 8192
  const int grid = B / 4;                       // 1 row/wave, 4 waves/block -> 2048

  hipLaunchKernelGGL(hedge_kernel, dim3(grid), dim3(256), 0, stream,
                     x, bn_g, bn_b, bn_m, bn_v, W_ih, b_ih, W_hh, b_hh,
                     W1, b1, W2, b2, out);
}

// Round 8
// 576.026 us; speedup vs baseline: 2.0860x; 2.0860x over previous
//
#include <hip/hip_runtime.h>
#include <math.h>

#define T_STEPS 512
#define NF 4
#define HID 32
#define BN_EPS 1e-5f

typedef float    f32x2 __attribute__((ext_vector_type(2)));
typedef float    f32x4 __attribute__((ext_vector_type(4)));
typedef _Float16 f16x2 __attribute__((ext_vector_type(2)));
typedef _Float16 f16x8 __attribute__((ext_vector_type(8)));

struct F8 { f16x2 p[4]; };   // 4 packed pairs == one f16x8 A/B fragment

__device__ __forceinline__ f16x2 pk16(float x, float y) {
  return __builtin_bit_cast(f16x2, __builtin_amdgcn_cvt_pkrtz(x, y));
}
__device__ __forceinline__ f16x8 mk8(f16x2 a, f16x2 b, f16x2 c, f16x2 d) {
  F8 f; f.p[0] = a; f.p[1] = b; f.p[2] = c; f.p[3] = d;
  return __builtin_bit_cast(f16x8, f);
}
__device__ __forceinline__ float fsigmoid(float x) {
  return __builtin_amdgcn_rcpf(1.0f + __expf(-x));   // validated r1..r7: absmax 2e-3
}
__device__ __forceinline__ float ftanh(float x) {
  return fmaf(__builtin_amdgcn_rcpf(1.0f + __expf(-2.0f * x)), 2.0f, -1.0f);
}
__device__ __forceinline__ f32x4 mfma16(f16x8 a, f16x8 b, f32x4 c) {
  return __builtin_amdgcn_mfma_f32_16x16x32_f16(a, b, c, 0, 0, 0);
}

// One wave per 16 batch rows; gates/MLP on the (idle) matrix pipe.
//   D/C layout: n = lane&15 (batch row), m = (lane>>4)*4 + reg.
//   A layout:   m = lane&15, k = (lane>>4)*8 + j.
//   B layout:   n = lane&15, k = (lane>>4)*8 + j.
// K-permutation trick: A columns are stored pre-permuted by
//   pi(8q+j) = (j<4) ? 4q+j : 16 + 4q + (j-4)
// so the D-layout h values (u = 16*pp + 4q + reg) pack DIRECTLY into the
// B fragment with 4 cvt_pkrtz — no LDS, no shuffles between steps.
__global__ __launch_bounds__(64, 2) void hedge_kernel(
    const float* __restrict__ x,
    const float* __restrict__ bn_g, const float* __restrict__ bn_b,
    const float* __restrict__ bn_m, const float* __restrict__ bn_v,
    const float* __restrict__ W_ih, const float* __restrict__ b_ih,
    const float* __restrict__ W_hh, const float* __restrict__ b_hh,
    const float* __restrict__ W1,   const float* __restrict__ b1,
    const float* __restrict__ W2,   const float* __restrict__ b2,
    float* __restrict__ out)
{
  const int lane = threadIdx.x;
  const int n    = lane & 15;          // batch column of the tile
  const int q    = lane >> 4;          // quad
  const int row  = blockIdx.x * 16 + n;

  // ---- fold BatchNorm (z*scale + shift) into A_ih and bias
  float scale[5], shift[5];
  #pragma unroll
  for (int f = 0; f < 5; ++f) {
    float s = bn_g[f] * rsqrtf(bn_v[f] + BN_EPS);
    scale[f] = s;
    shift[f] = fmaf(-bn_m[f], s, bn_b[f]);
  }

  const f16x2 zz = {(_Float16)0, (_Float16)0};

  // ---- A_hh[g]: W_hh rows 16g+m, K-permuted cols {4q..4q+3, 16+4q..16+4q+3}
  f16x8 Ahh[8];
  #pragma unroll
  for (int g = 0; g < 8; ++g) {
    const float* Wr = &W_hh[(16 * g + n) * HID];
    const f32x4 lo = *(const f32x4*)&Wr[4 * q];
    const f32x4 hi = *(const f32x4*)&Wr[16 + 4 * q];
    Ahh[g] = mk8(pk16(lo.x, lo.y), pk16(lo.z, lo.w),
                 pk16(hi.x, hi.y), pk16(hi.z, hi.w));
  }
  // ---- A_ih[g]: BN-scaled W_ih in z-slots k=0..4 (q==0 lanes only)
  f16x8 Aih[8];
  #pragma unroll
  for (int g = 0; g < 8; ++g) {
    const int r = 16 * g + n;
    const float w0 = W_ih[r * 5 + 0] * scale[0];
    const float w1 = W_ih[r * 5 + 1] * scale[1];
    const float w2 = W_ih[r * 5 + 2] * scale[2];
    const float w3 = W_ih[r * 5 + 3] * scale[3];
    const float w4 = W_ih[r * 5 + 4] * scale[4];
    Aih[g] = mk8(q == 0 ? pk16(w0, w1) : zz,
                 q == 0 ? pk16(w2, w3) : zz,
                 q == 0 ? pk16(w4, 0.f) : zz, zz);
  }
  // ---- C-init biases: bias[row] = b_ih + b_hh + Wih·bn_shift, at m = 4q+reg
  f32x4 Cb[8];
  #pragma unroll
  for (int g = 0; g < 8; ++g) {
    #pragma unroll
    for (int r2 = 0; r2 < 4; ++r2) {
      const int rr = 16 * g + 4 * q + r2;
      float a = b_ih[rr] + b_hh[rr];
      #pragma unroll
      for (int f = 0; f < 5; ++f) a = fmaf(W_ih[rr * 5 + f], shift[f], a);
      Cb[g][r2] = a;
    }
  }
  // ---- MLP: A_w1 (same K-permutation), C-init b1, per-lane W2 slice
  f16x8 Aw1[2];
  f32x4 Cb1[2];
  f32x4 W2v[2];
  #pragma unroll
  for (int p = 0; p < 2; ++p) {
    const float* Wr = &W1[(16 * p + n) * HID];
    const f32x4 lo = *(const f32x4*)&Wr[4 * q];
    const f32x4 hi = *(const f32x4*)&Wr[16 + 4 * q];
    Aw1[p] = mk8(pk16(lo.x, lo.y), pk16(lo.z, lo.w),
                 pk16(hi.x, hi.y), pk16(hi.z, hi.w));
    #pragma unroll
    for (int r2 = 0; r2 < 4; ++r2) {
      Cb1[p][r2] = b1[16 * p + 4 * q + r2];
      W2v[p][r2] = W2[16 * p + 4 * q + r2];
    }
  }
  const float b2s = b2[0];

  const float* xrow = x + (size_t)row * (T_STEPS * NF);
  float*       orow = out + (size_t)row * T_STEPS;

  // loop state: c (8 per lane, units u = 16*pp + 4q + reg), d, Bh fragment
  float cst[2][4] = {{0, 0, 0, 0}, {0, 0, 0, 0}};
  float d = 0.0f;
  f16x8 Bh = mk8(zz, zz, zz, zz);          // h_{-1} = 0
  f32x4 xv = *(const f32x4*)xrow;          // x_0 (q-duplicated, coalesced)

  #pragma unroll 1
  for (int t = 0; t < T_STEPS; ++t) {
    const int tn = (t + 1 < T_STEPS) ? t + 1 : t;
    const f32x4 xn = *(const f32x4*)(xrow + tn * NF);   // prefetch x_{t+1}

    // ---- B_z: z = [x_t, d] in slots k=0..4 (q==0), zeros elsewhere
    const f16x8 Bz = mk8(q == 0 ? pk16(xv.x, xv.y) : zz,
                         q == 0 ? pk16(xv.z, xv.w) : zz,
                         q == 0 ? pk16(d, 0.f) : zz, zz);

    // ---- gates: D[g] = W_ih'·z + W_hh·h + bias   (16 MFMA, matrix pipe)
    f32x4 D[8];
    #pragma unroll
    for (int g = 0; g < 8; ++g)
      D[g] = mfma16(Aih[g], Bz, mfma16(Ahh[g], Bh, Cb[g]));

    // ---- activations + c/h update (i: D0/1, f: D2/3, g: D4/5, o: D6/7)
    float hN[8];
    #pragma unroll
    for (int pp = 0; pp < 2; ++pp) {
      #pragma unroll
      for (int r2 = 0; r2 < 4; ++r2) {
        const float I = fsigmoid(D[0 + pp][r2]);
        const float F = fsigmoid(D[2 + pp][r2]);
        const float G = ftanh(D[4 + pp][r2]);
        const float O = fsigmoid(D[6 + pp][r2]);
        float& c = cst[pp][r2];
        c = fmaf(F, c, I * G);
        hN[pp * 4 + r2] = O * ftanh(c);
      }
    }
    // ---- new Bh fragment: slot j<4 -> u=4q+j (pp=0), j>=4 -> u=16+4q+(j-4)
    Bh = mk8(pk16(hN[0], hN[1]), pk16(hN[2], hN[3]),
             pk16(hN[4], hN[5]), pk16(hN[6], hN[7]));

    // ---- decision MLP: m = W1·h + b1 (2 MFMA), relu, W2-dot, reduce over q
    const f32x4 M0 = mfma16(Aw1[0], Bh, Cb1[0]);
    const f32x4 M1 = mfma16(Aw1[1], Bh, Cb1[1]);
    float y = 0.0f;
    #pragma unroll
    for (int r2 = 0; r2 < 4; ++r2) {
      y = fmaf(W2v[0][r2], fmaxf(M0[r2], 0.0f), y);
      y = fmaf(W2v[1][r2], fmaxf(M1[r2], 0.0f), y);
    }
    // sum the 4 q-partials for this n: xor16 (ds_swizzle) then xor32 (bpermute)
    y += __builtin_bit_cast(float, __builtin_amdgcn_ds_swizzle(
             __builtin_bit_cast(int, y), 0x401F));
    y += __shfl_xor(y, 32);
    d = fsigmoid(y + b2s);

    if (q == 0) orow[t] = d;
    xv = xn;
  }
}

extern "C" void kernel_launch(void* const* d_in, const int* in_sizes, int n_in,
                              void* d_out, int out_size, void* d_ws, size_t ws_size,
                              hipStream_t stream) {
  const float* x    = (const float*)d_in[0];
  const float* bn_g = (const float*)d_in[1];
  const float* bn_b = (const float*)d_in[2];
  const float* bn_m = (const float*)d_in[3];
  const float* bn_v = (const float*)d_in[4];
  const float* W_ih = (const float*)d_in[5];
  const float* b_ih = (const float*)d_in[6];
  const float* W_hh = (const float*)d_in[7];
  const float* b_hh = (const float*)d_in[8];
  const float* W1   = (const float*)d_in[9];
  const float* b1   = (const float*)d_in[10];
  const float* W2   = (const float*)d_in[11];
  const float* b2   = (const float*)d_in[12];
  float* out = (float*)d_out;

  const int B = in_sizes[0] / (T_STEPS * NF);   // 8192
  const int grid = B / 16;                      // 16 rows per 64-thread wave-block

  hipLaunchKernelGGL(hedge_kernel, dim3(grid), dim3(64), 0, stream,
                     x, bn_g, bn_b, bn_m, bn_v, W_ih, b_ih, W_hh, b_hh,
                     W1, b1, W2, b2, out);
}

// Round 9
// 558.174 us; speedup vs baseline: 2.1527x; 1.0320x over previous
//
#include <hip/hip_runtime.h>
#include <math.h>

#define T_STEPS 512
#define NF 4
#define HID 32
#define BN_EPS 1e-5f
#define LOG2E 1.44269504088896340736f

typedef float    f32x2 __attribute__((ext_vector_type(2)));
typedef float    f32x4 __attribute__((ext_vector_type(4)));
typedef _Float16 f16x2 __attribute__((ext_vector_type(2)));
typedef _Float16 f16x8 __attribute__((ext_vector_type(8)));

struct F8 { f16x2 p[4]; };

__device__ __forceinline__ f16x2 pk16(float x, float y) {
  return __builtin_bit_cast(f16x2, __builtin_amdgcn_cvt_pkrtz(x, y));
}
__device__ __forceinline__ f16x8 mk8(f16x2 a, f16x2 b, f16x2 c, f16x2 d) {
  F8 f; f.p[0] = a; f.p[1] = b; f.p[2] = c; f.p[3] = d;
  return __builtin_bit_cast(f16x8, f);
}
#if __has_builtin(__builtin_amdgcn_exp2f)
__device__ __forceinline__ float ex2(float x) { return __builtin_amdgcn_exp2f(x); }
#else
__device__ __forceinline__ float ex2(float x) { return exp2f(x); }
#endif
__device__ __forceinline__ float fsigmoid(float x) {
  return __builtin_amdgcn_rcpf(1.0f + __expf(-x));   // validated r1..r8
}
__device__ __forceinline__ f32x4 mfma16(f16x8 a, f16x8 b, f32x4 c) {
  return __builtin_amdgcn_mfma_f32_16x16x32_f16(a, b, c, 0, 0, 0);
}

// 4 waves per 16-row tile, one GATE per wave (0:i 1:f 2:g 3:o) -> 2048 waves,
// 2/SIMD (r8 had 512 waves, 1 on half the SIMDs). Per-wave trans 80 -> ~34.
// Gate pre-activations are pre-scaled by ke = -log2e (or -2log2e for g) inside
// the f16 weights/bias so activation = a*rcp(1+exp2(D)) + b (no per-elem mul).
// d is OUT of the MFMA operands: W1·h rides the next step's Bh-multiply and
// wd·d is a VALU post-add -> the swizzle/shfl d-reduce runs in the MFMA shadow.
// Activated gates exchange via double-buffered LDS, ONE barrier/step.
__global__ __launch_bounds__(256, 2) void hedge_kernel(
    const float* __restrict__ x,
    const float* __restrict__ bn_g, const float* __restrict__ bn_b,
    const float* __restrict__ bn_m, const float* __restrict__ bn_v,
    const float* __restrict__ W_ih, const float* __restrict__ b_ih,
    const float* __restrict__ W_hh, const float* __restrict__ b_hh,
    const float* __restrict__ W1,   const float* __restrict__ b1,
    const float* __restrict__ W2,   const float* __restrict__ b2,
    float* __restrict__ out)
{
  // [buf][gate][pp][q][n] of f32x4 (r2) — writes/reads are whole f32x4,
  // 8 balanced bank groups -> phase-balanced b128 access. 16 KB.
  __shared__ f32x4 sact[2][4][2][4][16];

  const int tid  = threadIdx.x;
  const int lane = tid & 63;
  const int w    = tid >> 6;           // wave id == gate id (uniform)
  const int n    = lane & 15;          // batch column
  const int q    = lane >> 4;          // quad
  const int row  = blockIdx.x * 16 + n;

  // ---- fold BatchNorm (z*scale + shift) into weights and bias
  float scale[5], shift[5];
  #pragma unroll
  for (int f = 0; f < 5; ++f) {
    float s = bn_g[f] * rsqrtf(bn_v[f] + BN_EPS);
    scale[f] = s;
    shift[f] = fmaf(-bn_m[f], s, bn_b[f]);
  }

  const float ke = (w == 2) ? -2.0f * LOG2E : -LOG2E;  // gate pre-scale
  const float aA = (w == 2) ?  2.0f : 1.0f;            // act = aA*rcp(1+2^D)+bA
  const float bA = (w == 2) ? -1.0f : 0.0f;

  const f16x2 zz = {(_Float16)0, (_Float16)0};

  // A/B layouts + K-permutation identical to r8 (verified):
  //   A: m=lane&15, k-slot j -> pi(8q+j) = (j<4) ? 4q+j : 16+4q+(j-4)
  //   D: n=lane&15, m=4q+reg
  f16x8 Ahh[2], Aih[2];
  f32x4 Cb[2], Wd[2];
  #pragma unroll
  for (int pp = 0; pp < 2; ++pp) {
    const int g = 2 * w + pp;                    // D-tile (gate-row block)
    const float* Wr = &W_hh[(16 * g + n) * HID];
    const f32x4 lo = *(const f32x4*)&Wr[4 * q];
    const f32x4 hi = *(const f32x4*)&Wr[16 + 4 * q];
    Ahh[pp] = mk8(pk16(ke * lo.x, ke * lo.y), pk16(ke * lo.z, ke * lo.w),
                  pk16(ke * hi.x, ke * hi.y), pk16(ke * hi.z, ke * hi.w));
    const float* Wi = &W_ih[(16 * g + n) * 5];
    Aih[pp] = mk8(q == 0 ? pk16(ke * Wi[0] * scale[0], ke * Wi[1] * scale[1]) : zz,
                  q == 0 ? pk16(ke * Wi[2] * scale[2], ke * Wi[3] * scale[3]) : zz,
                  zz, zz);
    #pragma unroll
    for (int r2 = 0; r2 < 4; ++r2) {
      const int rr = 16 * g + 4 * q + r2;
      float a = b_ih[rr] + b_hh[rr];
      #pragma unroll
      for (int f = 0; f < 5; ++f) a = fmaf(W_ih[rr * 5 + f], shift[f], a);
      Cb[pp][r2] = ke * a;
      Wd[pp][r2] = ke * W_ih[rr * 5 + 4] * scale[4];
    }
  }
  // MLP fragments (unscaled), redundant in every wave (keeps d local)
  f16x8 Aw1[2];
  f32x4 Cb1[2], W2v[2];
  #pragma unroll
  for (int p = 0; p < 2; ++p) {
    const float* Wr = &W1[(16 * p + n) * HID];
    const f32x4 lo = *(const f32x4*)&Wr[4 * q];
    const f32x4 hi = *(const f32x4*)&Wr[16 + 4 * q];
    Aw1[p] = mk8(pk16(lo.x, lo.y), pk16(lo.z, lo.w),
                 pk16(hi.x, hi.y), pk16(hi.z, hi.w));
    #pragma unroll
    for (int r2 = 0; r2 < 4; ++r2) {
      Cb1[p][r2] = b1[16 * p + 4 * q + r2];
      W2v[p][r2] = W2[16 * p + 4 * q + r2];
    }
  }
  const float b2s = b2[0];

  const float* xrow = x + (size_t)row * (T_STEPS * NF);
  float*       orow = out + (size_t)row * T_STEPS;

  float cst0[4] = {0, 0, 0, 0}, cst1[4] = {0, 0, 0, 0};
  f16x8 Bh = mk8(zz, zz, zz, zz);          // h_{-1} = 0
  f32x4 xv = *(const f32x4*)xrow;          // x_0

  #pragma unroll 1
  for (int t = 0; t < T_STEPS; ++t) {
    const int tn = (t + 1 < T_STEPS) ? t + 1 : t;
    const f32x4 xn = *(const f32x4*)(xrow + tn * NF);   // prefetch x_{t+1}
    const int bsel = t & 1;

    // ---- MFMA block: gates(t) from h_{t-1},x_t  AND  MLP(h_{t-1}) -> d_{t-1}
    const f16x8 Bz = mk8(q == 0 ? pk16(xv.x, xv.y) : zz,
                         q == 0 ? pk16(xv.z, xv.w) : zz, zz, zz);
    f32x4 D0 = mfma16(Aih[0], Bz, mfma16(Ahh[0], Bh, Cb[0]));
    f32x4 D1 = mfma16(Aih[1], Bz, mfma16(Ahh[1], Bh, Cb[1]));
    const f32x4 M0 = mfma16(Aw1[0], Bh, Cb1[0]);
    const f32x4 M1 = mfma16(Aw1[1], Bh, Cb1[1]);

    // ---- d_{t-1} = sigmoid(relu(M)·W2 + b2)  (off critical path of D)
    float y = 0.0f;
    #pragma unroll
    for (int r2 = 0; r2 < 4; ++r2) {
      y = fmaf(W2v[0][r2], fmaxf(M0[r2], 0.0f), y);
      y = fmaf(W2v[1][r2], fmaxf(M1[r2], 0.0f), y);
    }
    y += __builtin_bit_cast(float, __builtin_amdgcn_ds_swizzle(
             __builtin_bit_cast(int, y), 0x401F));      // xor-16 (q^1)
    y += __shfl_xor(y, 32);                             // q^2
    float dl = fsigmoid(y + b2s);
    dl = t ? dl : 0.0f;                                 // reference d_{-1} = 0
    if (w == 0 && q == 0 && t) orow[t - 1] = dl;

    // ---- d-term post-add (Wd is ke-scaled like D), then activation
    f32x4 A0, A1;
    #pragma unroll
    for (int r2 = 0; r2 < 4; ++r2) {
      const float d0 = fmaf(Wd[0][r2], dl, D0[r2]);
      const float d1 = fmaf(Wd[1][r2], dl, D1[r2]);
      A0[r2] = fmaf(aA, __builtin_amdgcn_rcpf(1.0f + ex2(d0)), bA);
      A1[r2] = fmaf(aA, __builtin_amdgcn_rcpf(1.0f + ex2(d1)), bA);
    }

    // ---- exchange activated gates (double buffer -> ONE barrier/step)
    sact[bsel][w][0][q][n] = A0;
    sact[bsel][w][1][q][n] = A1;
    __syncthreads();
    const f32x4 Iv0 = sact[bsel][0][0][q][n], Iv1 = sact[bsel][0][1][q][n];
    const f32x4 Fv0 = sact[bsel][1][0][q][n], Fv1 = sact[bsel][1][1][q][n];
    const f32x4 Gv0 = sact[bsel][2][0][q][n], Gv1 = sact[bsel][2][1][q][n];
    const f32x4 Ov0 = sact[bsel][3][0][q][n], Ov1 = sact[bsel][3][1][q][n];

    // ---- c/h update (redundant in all 4 waves; keeps Bh local, no 2nd barrier)
    float hN[8];
    #pragma unroll
    for (int r2 = 0; r2 < 4; ++r2) {
      float cc0 = fmaf(Fv0[r2], cst0[r2], Iv0[r2] * Gv0[r2]);
      float cc1 = fmaf(Fv1[r2], cst1[r2], Iv1[r2] * Gv1[r2]);
      cst0[r2] = cc0; cst1[r2] = cc1;
      const float tc0 = fmaf(2.0f, __builtin_amdgcn_rcpf(1.0f + ex2(-2.0f * LOG2E * cc0)), -1.0f);
      const float tc1 = fmaf(2.0f, __builtin_amdgcn_rcpf(1.0f + ex2(-2.0f * LOG2E * cc1)), -1.0f);
      hN[r2]     = Ov0[r2] * tc0;
      hN[4 + r2] = Ov1[r2] * tc1;
    }
    Bh = mk8(pk16(hN[0], hN[1]), pk16(hN[2], hN[3]),
             pk16(hN[4], hN[5]), pk16(hN[6], hN[7]));
    xv = xn;
  }

  // ---- epilogue: d_{T-1} from h_{T-1}
  const f32x4 M0 = mfma16(Aw1[0], Bh, Cb1[0]);
  const f32x4 M1 = mfma16(Aw1[1], Bh, Cb1[1]);
  float y = 0.0f;
  #pragma unroll
  for (int r2 = 0; r2 < 4; ++r2) {
    y = fmaf(W2v[0][r2], fmaxf(M0[r2], 0.0f), y);
    y = fmaf(W2v[1][r2], fmaxf(M1[r2], 0.0f), y);
  }
  y += __builtin_bit_cast(float, __builtin_amdgcn_ds_swizzle(
           __builtin_bit_cast(int, y), 0x401F));
  y += __shfl_xor(y, 32);
  const float dl = fsigmoid(y + b2s);
  if (w == 0 && q == 0) orow[T_STEPS - 1] = dl;
}

extern "C" void kernel_launch(void* const* d_in, const int* in_sizes, int n_in,
                              void* d_out, int out_size, void* d_ws, size_t ws_size,
                              hipStream_t stream) {
  const float* x    = (const float*)d_in[0];
  const float* bn_g = (const float*)d_in[1];
  const float* bn_b = (const float*)d_in[2];
  const float* bn_m = (const float*)d_in[3];
  const float* bn_v = (const float*)d_in[4];
  const float* W_ih = (const float*)d_in[5];
  const float* b_ih = (const float*)d_in[6];
  const float* W_hh = (const float*)d_in[7];
  const float* b_hh = (const float*)d_in[8];
  const float* W1   = (const float*)d_in[9];
  const float* b1   = (const float*)d_in[10];
  const float* W2   = (const float*)d_in[11];
  const float* b2   = (const float*)d_in[12];
  float* out = (float*)d_out;

  const int B = in_sizes[0] / (T_STEPS * NF);   // 8192
  const int grid = B / 16;                      // 16 rows per 4-wave block -> 512

  hipLaunchKernelGGL(hedge_kernel, dim3(grid), dim3(256), 0, stream,
                     x, bn_g, bn_b, bn_m, bn_v, W_ih, b_ih, W_hh, b_hh,
                     W1, b1, W2, b2, out);
}